// Round 8
// baseline (250.960 us; speedup 1.0000x reference)
//
#include <hip/hip_runtime.h>
#include <hip/hip_bf16.h>
#include <math.h>
#include <type_traits>

#define Bz 8
#define Tz 1024
#define Cz 1024
#define Hz 16
#define HDz 64
#define Mz (Bz*Tz)        // 8192 tokens
#define N1 (3*Cz)         // 3072 qkv width

typedef __attribute__((ext_vector_type(8))) short short8;
typedef __attribute__((ext_vector_type(4))) short short4v;
typedef __attribute__((ext_vector_type(4))) float floatx4;

__device__ __forceinline__ unsigned short f2bf(float f) {
    unsigned u = __float_as_uint(f);
    return (unsigned short)((u + 0x7FFFu + ((u >> 16) & 1u)) >> 16);
}

// pack two f32 -> bf16x2 dword (RNE; v_cvt_pk_bf16_f32 on gfx950)
__device__ __forceinline__ unsigned pkbf(float a, float b) {
    __hip_bfloat162 h = __float22bfloat162_rn(make_float2(a, b));
    return *(unsigned*)&h;
}

// async global->LDS, 16 B per lane, dest = uniform base + lane*16
__device__ __forceinline__ void gload16(const void* g, void* l) {
    __builtin_amdgcn_global_load_lds(
        (const __attribute__((address_space(1))) unsigned int*)g,
        (__attribute__((address_space(3))) unsigned int*)l, 16, 0, 0);
}

// ---------------------------------------------------------------------------
// Merged prep: x fp32->bf16  +  Wqkv / Wproj transpose+convert.
// blockIdx.x ranges:  [0,8192) cvt   [8192,11264) Wqkv   [11264,12288) Wproj
// ---------------------------------------------------------------------------
__global__ __launch_bounds__(256) void prep_kernel(
    const float* __restrict__ x, unsigned short* __restrict__ xb,
    const float* __restrict__ Wqkv, unsigned short* __restrict__ Wqkvt,
    const float* __restrict__ Wproj, unsigned short* __restrict__ Wprojt)
{
    __shared__ float tile[32][33];
    const int bid = blockIdx.x;
    const int tid = threadIdx.x;
    if (bid < 8192) {
        int i = bid * 256 + tid;                  // 4 elems each
        float4 v = *(const float4*)&x[(size_t)i * 4];
        ushort4 o;
        o.x = f2bf(v.x); o.y = f2bf(v.y); o.z = f2bf(v.z); o.w = f2bf(v.w);
        *(ushort4*)&xb[(size_t)i * 4] = o;
        return;
    }
    const float* W; unsigned short* Wt; int K, N, n0, k0;
    if (bid < 11264) {
        int b = bid - 8192;  W = Wqkv;  Wt = Wqkvt;  K = Cz; N = N1;
        n0 = (b % 96) * 32;  k0 = (b / 96) * 32;
    } else {
        int b = bid - 11264; W = Wproj; Wt = Wprojt; K = Cz; N = Cz;
        n0 = (b % 32) * 32;  k0 = (b / 32) * 32;
    }
    const int tx = tid & 31, ty = tid >> 5;       // (32,8)
#pragma unroll
    for (int i = 0; i < 4; ++i)
        tile[ty + i * 8][tx] = W[(size_t)(k0 + ty + i * 8) * N + n0 + tx];
    __syncthreads();
#pragma unroll
    for (int i = 0; i < 4; ++i)
        Wt[(size_t)(n0 + ty + i * 8) * K + k0 + tx] = f2bf(tile[tx][ty + i * 8]);
}

// ---------------------------------------------------------------------------
// V-part of qkvb -> Vt[bh][d][t] bf16, LDS-tile transpose (64 t x 64 d).
// ---------------------------------------------------------------------------
__global__ __launch_bounds__(256) void vtrans_kernel(const unsigned short* __restrict__ qkvb,
    unsigned short* __restrict__ Vt)
{
    __shared__ unsigned short tile[64][72];
    const int t0 = blockIdx.x * 64;
    const int bh = blockIdx.y;
    const int b = bh >> 4, h = bh & 15;
    const int tid = threadIdx.x;
#pragma unroll
    for (int it = 0; it < 2; ++it) {
        int idx = tid + it * 256;           // 0..511
        int tl = idx >> 3, d8 = idx & 7;
        *(short8*)&tile[tl][d8 * 8] =
            *(const short8*)&qkvb[(size_t)(b * Tz + t0 + tl) * N1 + 2 * Cz + h * HDz + d8 * 8];
    }
    __syncthreads();
#pragma unroll
    for (int it = 0; it < 2; ++it) {
        int idx = tid + it * 256;
        int d = idx >> 3, t8 = idx & 7;
        unsigned short o[8];
#pragma unroll
        for (int j = 0; j < 8; ++j) o[j] = tile[t8 * 8 + j][d];
        *(short8*)&Vt[(size_t)bh * (HDz * Tz) + (size_t)d * Tz + t0 + t8 * 8] = *(short8*)o;
    }
}

// ---------------------------------------------------------------------------
// bf16 MFMA GEMM: C = A[M][K] @ Bt[N][K]^T + bias. 128x128 tile, BK=64,
// XOR-chunk source swizzle on staging, unswizzled at fragment read.
// ---------------------------------------------------------------------------
__global__ __launch_bounds__(256) void gemm_kernel(const unsigned short* __restrict__ A,
    const unsigned short* __restrict__ Bt, const float* __restrict__ bias,
    void* __restrict__ Cout, int M, int N, int K, int outBf16)
{
    __shared__ unsigned short As[128 * 64];
    __shared__ unsigned short Bs[128 * 64];
    const int tid = threadIdx.x;
    const int lane = tid & 63;
    const int w = tid >> 6, wr = w >> 1, wc = w & 1;
    const int quad = lane >> 4, m16 = lane & 15;
    const int row0 = blockIdx.y * 128, col0 = blockIdx.x * 128;

    float bv[4];
#pragma unroll
    for (int ni = 0; ni < 4; ++ni)
        bv[ni] = bias[col0 + wc * 64 + ni * 16 + m16];

    floatx4 acc[4][4];
#pragma unroll
    for (int mi = 0; mi < 4; ++mi)
#pragma unroll
        for (int ni = 0; ni < 4; ++ni)
            acc[mi][ni] = (floatx4){0.f, 0.f, 0.f, 0.f};

    const int l3 = lane >> 3;                   // row-within-call (and row&7)
    const int swz = ((lane & 7) ^ l3) * 8;      // source chunk swizzle (elems)
    const unsigned short* gA[4];
    const unsigned short* gB[4];
    unsigned short* lA[4];
    unsigned short* lB[4];
#pragma unroll
    for (int i = 0; i < 4; ++i) {
        int c = w * 4 + i;                      // call id, rows c*8..c*8+7
        gA[i] = A  + (size_t)(row0 + c * 8 + l3) * K + swz;
        gB[i] = Bt + (size_t)(col0 + c * 8 + l3) * K + swz;
        lA[i] = &As[c * 512];
        lB[i] = &Bs[c * 512];
    }
    const int sw7 = m16 & 7;                    // frag-read swizzle key

    for (int k0 = 0; k0 < K; k0 += 64) {
#pragma unroll
        for (int i = 0; i < 4; ++i) {
            gload16(gA[i] + k0, lA[i]);
            gload16(gB[i] + k0, lB[i]);
        }
        __syncthreads();
#pragma unroll
        for (int s = 0; s < 2; ++s) {
            short8 af[4], bfr[4];
            const int ch = ((s * 4 + quad) ^ sw7) * 8;
#pragma unroll
            for (int mi = 0; mi < 4; ++mi)
                af[mi] = *(short8*)&As[(wr * 64 + mi * 16 + m16) * 64 + ch];
#pragma unroll
            for (int ni = 0; ni < 4; ++ni)
                bfr[ni] = *(short8*)&Bs[(wc * 64 + ni * 16 + m16) * 64 + ch];
#pragma unroll
            for (int mi = 0; mi < 4; ++mi)
#pragma unroll
                for (int ni = 0; ni < 4; ++ni)
                    acc[mi][ni] = __builtin_amdgcn_mfma_f32_16x16x32_bf16(af[mi], bfr[ni], acc[mi][ni], 0, 0, 0);
        }
        __syncthreads();
    }

#pragma unroll
    for (int mi = 0; mi < 4; ++mi)
#pragma unroll
        for (int ni = 0; ni < 4; ++ni)
#pragma unroll
            for (int reg = 0; reg < 4; ++reg) {
                int r = row0 + wr * 64 + mi * 16 + quad * 4 + reg;
                int c = col0 + wc * 64 + ni * 16 + m16;
                float v = acc[mi][ni][reg] + bv[ni];
                if (outBf16) ((unsigned short*)Cout)[(size_t)r * N + c] = f2bf(v);
                else         ((float*)Cout)[(size_t)r * N + c] = v;
            }
}

// ---------------------------------------------------------------------------
// MFMA causal flash attention, transposed formulation, load-balanced,
// 2-wave blocks, 32 q-rows/wave. VALU-minimized inner tile:
//  - diag vs non-diag tile bodies split statically (no mask ops off-diagonal)
//  - P^T packed with v_cvt_pk_bf16_f32 (one op per 2 elems)
//  - softmax denominator l accumulated by MFMA with a ones-A-fragment
//    (row 0 of C = sum over keys); no scalar psum adds in the loop.
// Grid (8, 128), block 128 thr = 2 waves; block bx does q-tiles {15-bx, bx}.
// ---------------------------------------------------------------------------
__global__ __launch_bounds__(128) void attn_kernel(const unsigned short* __restrict__ qkvb,
    const unsigned short* __restrict__ VtG, unsigned short* __restrict__ attb)
{
    __shared__ unsigned short Ks[2][64 * 64];   // [key][d swizzled]
    __shared__ unsigned short Vs[2][64 * 64];   // [d][key swizzled]

    const int bx = blockIdx.x;                  // 0..7
    const int bh = blockIdx.y;
    const int b = bh >> 4, h = bh & 15;
    const int tid = threadIdx.x, lane = tid & 63, w = tid >> 6;   // w in {0,1}
    const int quad = lane >> 4, m16 = lane & 15;
    const int qis[2] = {15 - bx, bx};           // big tile first

    const unsigned short* Kb = qkvb + (size_t)(b * Tz) * N1 + Cz + h * HDz;
    const unsigned short* Vb = VtG + (size_t)bh * (HDz * Tz);

    const int l3 = lane >> 3, l7 = lane & 7;
    const int gsw = ((l7 ^ l3) << 3);           // staging source swizzle
    const int sw = m16 & 7;                     // read-side row swizzle key
    const int p0 = (quad ^ sw) << 3;            // K-frag group offset (elems)

    // ones A-frag for the l-sum MFMA: A[m=0][k]=1, else 0
    short8 onesf = (short8){0,0,0,0,0,0,0,0};
    if (m16 == 0) {
        const short one = (short)0x3F80;
        onesf = (short8){one,one,one,one,one,one,one,one};
    }

    // staging rows for this wave: w*32 + i*8 + l3, i=0..3 (K and V alike)
    int srow[4];
#pragma unroll
    for (int i = 0; i < 4; ++i) srow[i] = w * 32 + i * 8 + l3;

    // prologue: stage key-tile 0 into buf 0
#pragma unroll
    for (int i = 0; i < 4; ++i) {
        gload16(Kb + (size_t)srow[i] * N1 + gsw, &Ks[0][(w * 4 + i) * 512]);
        gload16(Vb + (size_t)srow[i] * Tz + gsw, &Vs[0][(w * 4 + i) * 512]);
    }

    int buf = 0;
    for (int t = 0; t < 2; ++t) {
        const int qi = qis[t];

        // Q B-frags: rows qi*64 + w*32 + mi*16 + m16
        short8 qf[2][2];
        int qrow[2];
#pragma unroll
        for (int mi = 0; mi < 2; ++mi) {
            qrow[mi] = qi * 64 + w * 32 + mi * 16 + m16;
            const size_t rq = (size_t)(b * Tz + qrow[mi]) * N1 + h * HDz;
            qf[mi][0] = *(const short8*)&qkvb[rq + quad * 8];
            qf[mi][1] = *(const short8*)&qkvb[rq + 32 + quad * 8];
        }

        floatx4 of[2][4];   // O^T accum: [d=dc*16+quad*4+reg][q=m16]
#pragma unroll
        for (int mi = 0; mi < 2; ++mi)
#pragma unroll
            for (int dc = 0; dc < 4; ++dc) of[mi][dc] = (floatx4){0.f, 0.f, 0.f, 0.f};
        floatx4 lsum[2];
        lsum[0] = (floatx4){0.f, 0.f, 0.f, 0.f};
        lsum[1] = (floatx4){0.f, 0.f, 0.f, 0.f};

        // ---- tile body, DIAG statically split ----
        auto tile_body = [&](auto diag_c) {
            constexpr bool DIAG = decltype(diag_c)::value;
            // w=0 on the diagonal: keys 32..63 fully masked
            constexpr int M0MAX = 4;            // bounded below per-wave
            short8 pf[2][2];
#pragma unroll
            for (int m0 = 0; m0 < M0MAX; ++m0) {
                if (DIAG && w == 0 && m0 >= 2) continue;
                const unsigned short* kr = &Ks[buf][(m0 * 16 + m16) * 64];
                short8 kf0 = *(const short8*)&kr[p0];
                short8 kf1 = *(const short8*)&kr[p0 ^ 32];
#pragma unroll
                for (int mi = 0; mi < 2; ++mi) {
                    floatx4 st = (floatx4){0.f, 0.f, 0.f, 0.f};
                    st = __builtin_amdgcn_mfma_f32_16x16x32_bf16(kf0, qf[mi][0], st, 0, 0, 0);
                    st = __builtin_amdgcn_mfma_f32_16x16x32_bf16(kf1, qf[mi][1], st, 0, 0, 0);
                    float p[4];
#pragma unroll
                    for (int reg = 0; reg < 4; ++reg) {
                        // exp(s/8) = exp2(s * 0.125*log2e)
                        p[reg] = exp2f(st[reg] * 0.18033688f);
                        if (DIAG) {
                            int key = m0 * 16 + quad * 4 + reg;   // within tile
                            int qr  = w * 32 + mi * 16 + m16;
                            p[reg] = (key <= qr) ? p[reg] : 0.f;
                        }
                    }
                    unsigned* pp = (unsigned*)&pf[mi][m0 >> 1];
                    pp[(m0 & 1) * 2 + 0] = pkbf(p[0], p[1]);
                    pp[(m0 & 1) * 2 + 1] = pkbf(p[2], p[3]);
                }
            }
            // ---- O^T += V^T · P^T, l += ones · P^T ----
#pragma unroll
            for (int kg = 0; kg < 2; ++kg) {
                if (DIAG && w == 0 && kg == 1) continue;
#pragma unroll
                for (int mi = 0; mi < 2; ++mi)
                    lsum[mi] = __builtin_amdgcn_mfma_f32_16x16x32_bf16(onesf, pf[mi][kg], lsum[mi], 0, 0, 0);
#pragma unroll
                for (int dc = 0; dc < 4; ++dc) {
                    const unsigned short* vrow = &Vs[buf][(dc * 16 + m16) * 64];
                    const int g0 = kg * 4 + (quad >> 1);
                    const int off = (quad & 1) * 4;
                    short4v v0 = *(const short4v*)&vrow[((g0 ^ sw) << 3) + off];
                    short4v v1 = *(const short4v*)&vrow[(((g0 + 2) ^ sw) << 3) + off];
                    short8 vf;
                    vf[0] = v0[0]; vf[1] = v0[1]; vf[2] = v0[2]; vf[3] = v0[3];
                    vf[4] = v1[0]; vf[5] = v1[1]; vf[6] = v1[2]; vf[7] = v1[3];
#pragma unroll
                    for (int mi = 0; mi < 2; ++mi)
                        of[mi][dc] = __builtin_amdgcn_mfma_f32_16x16x32_bf16(vf, pf[mi][kg], of[mi][dc], 0, 0, 0);
                }
            }
        };

        for (int ki = 0; ki <= qi; ++ki) {
            __syncthreads();   // drains staging for tile ki; prev reads done
            // prefetch: next ki, or ki=0 of the second q-tile at the seam
            const int nk = (ki < qi) ? (ki + 1) : (t == 0 ? 0 : -1);
            if (nk >= 0) {
                const size_t ko = (size_t)nk * 64;
#pragma unroll
                for (int i = 0; i < 4; ++i) {
                    gload16(Kb + (ko + srow[i]) * N1 + gsw, &Ks[buf ^ 1][(w * 4 + i) * 512]);
                    gload16(Vb + (size_t)srow[i] * Tz + ko + gsw, &Vs[buf ^ 1][(w * 4 + i) * 512]);
                }
            }
            if (ki == qi) tile_body(std::true_type{});
            else          tile_body(std::false_type{});
            buf ^= 1;
        }

        // ---- l lives in C row 0 (quad 0, reg 0); broadcast + store ----
#pragma unroll
        for (int mi = 0; mi < 2; ++mi) {
            const float l = __shfl(lsum[mi][0], m16);   // from lanes 0..15
            const float inv = 1.f / l;
            const size_t orow = (size_t)(b * Tz + qrow[mi]) * Cz + h * HDz;
#pragma unroll
            for (int dc = 0; dc < 4; ++dc) {
                ushort4 o;
                o.x = f2bf(of[mi][dc][0] * inv);
                o.y = f2bf(of[mi][dc][1] * inv);
                o.z = f2bf(of[mi][dc][2] * inv);
                o.w = f2bf(of[mi][dc][3] * inv);
                *(ushort4*)&attb[orow + dc * 16 + quad * 4] = o;
            }
        }
    }
}

// ---------------------------------------------------------------------------
extern "C" void kernel_launch(void* const* d_in, const int* in_sizes, int n_in,
                              void* d_out, int out_size, void* d_ws, size_t ws_size,
                              hipStream_t stream)
{
    const float* x     = (const float*)d_in[0];
    const float* Wqkv  = (const float*)d_in[1];
    const float* bqkv  = (const float*)d_in[2];
    const float* Wproj = (const float*)d_in[3];
    const float* bproj = (const float*)d_in[4];
    float* out = (float*)d_out;

    unsigned short* xb     = (unsigned short*)d_ws;              // 16 MB
    unsigned short* Wqkvt  = xb + (size_t)Mz * Cz;               //  6 MB
    unsigned short* Wprojt = Wqkvt + (size_t)N1 * Cz;            //  2 MB
    unsigned short* qkvb   = Wprojt + (size_t)Cz * Cz;           // 48 MB
    unsigned short* VtG    = qkvb + (size_t)Mz * N1;             // 16 MB
    unsigned short* attb   = VtG + (size_t)(Bz * Hz) * HDz * Tz; // 16 MB

    prep_kernel<<<12288, 256, 0, stream>>>(x, xb, Wqkv, Wqkvt, Wproj, Wprojt);

    gemm_kernel<<<dim3(N1 / 128, Mz / 128), 256, 0, stream>>>(
        xb, Wqkvt, bqkv, qkvb, Mz, N1, Cz, 1);

    vtrans_kernel<<<dim3(Tz / 64, Bz * Hz), 256, 0, stream>>>(qkvb, VtG);

    attn_kernel<<<dim3(8, Bz * Hz), 128, 0, stream>>>(qkvb, VtG, attb);

    gemm_kernel<<<dim3(Cz / 128, Mz / 128), 256, 0, stream>>>(
        attb, Wprojt, bproj, out, Mz, Cz, Cz, 0);
}

// Round 9
// 247.550 us; speedup vs baseline: 1.0138x; 1.0138x over previous
//
#include <hip/hip_runtime.h>
#include <hip/hip_bf16.h>
#include <math.h>
#include <type_traits>

#define Bz 8
#define Tz 1024
#define Cz 1024
#define Hz 16
#define HDz 64
#define Mz (Bz*Tz)        // 8192 tokens
#define N1 (3*Cz)         // 3072 qkv width
#define QKN 2048          // Q+K buffer row stride

typedef __attribute__((ext_vector_type(8))) short short8;
typedef __attribute__((ext_vector_type(4))) short short4v;
typedef __attribute__((ext_vector_type(4))) float floatx4;

__device__ __forceinline__ unsigned short f2bf(float f) {
    unsigned u = __float_as_uint(f);
    return (unsigned short)((u + 0x7FFFu + ((u >> 16) & 1u)) >> 16);
}

// pack two f32 -> bf16x2 dword (RNE; v_cvt_pk_bf16_f32 on gfx950)
__device__ __forceinline__ unsigned pkbf(float a, float b) {
    __hip_bfloat162 h = __float22bfloat162_rn(make_float2(a, b));
    return *(unsigned*)&h;
}

// async global->LDS, 16 B per lane, dest = uniform base + lane*16
__device__ __forceinline__ void gload16(const void* g, void* l) {
    __builtin_amdgcn_global_load_lds(
        (const __attribute__((address_space(1))) unsigned int*)g,
        (__attribute__((address_space(3))) unsigned int*)l, 16, 0, 0);
}

// ---------------------------------------------------------------------------
// Merged prep: x fp32->bf16  +  Wqkv / Wproj transpose+convert.
// blockIdx.x ranges:  [0,8192) cvt   [8192,11264) Wqkv   [11264,12288) Wproj
// ---------------------------------------------------------------------------
__global__ __launch_bounds__(256) void prep_kernel(
    const float* __restrict__ x, unsigned short* __restrict__ xb,
    const float* __restrict__ Wqkv, unsigned short* __restrict__ Wqkvt,
    const float* __restrict__ Wproj, unsigned short* __restrict__ Wprojt)
{
    __shared__ float tile[32][33];
    const int bid = blockIdx.x;
    const int tid = threadIdx.x;
    if (bid < 8192) {
        int i = bid * 256 + tid;                  // 4 elems each
        float4 v = *(const float4*)&x[(size_t)i * 4];
        ushort4 o;
        o.x = f2bf(v.x); o.y = f2bf(v.y); o.z = f2bf(v.z); o.w = f2bf(v.w);
        *(ushort4*)&xb[(size_t)i * 4] = o;
        return;
    }
    const float* W; unsigned short* Wt; int K, N, n0, k0;
    if (bid < 11264) {
        int b = bid - 8192;  W = Wqkv;  Wt = Wqkvt;  K = Cz; N = N1;
        n0 = (b % 96) * 32;  k0 = (b / 96) * 32;
    } else {
        int b = bid - 11264; W = Wproj; Wt = Wprojt; K = Cz; N = Cz;
        n0 = (b % 32) * 32;  k0 = (b / 32) * 32;
    }
    const int tx = tid & 31, ty = tid >> 5;       // (32,8)
#pragma unroll
    for (int i = 0; i < 4; ++i)
        tile[ty + i * 8][tx] = W[(size_t)(k0 + ty + i * 8) * N + n0 + tx];
    __syncthreads();
#pragma unroll
    for (int i = 0; i < 4; ++i)
        Wt[(size_t)(n0 + ty + i * 8) * K + k0 + tx] = f2bf(tile[tx][ty + i * 8]);
}

// ---------------------------------------------------------------------------
// bf16 MFMA GEMM: C = A[M][K] @ Bt[N][K]^T + bias. 128x128 tile, BK=64,
// XOR-chunk source swizzle on staging, unswizzled at fragment read.
// mode 0: fp32 out, row stride N (proj).
// mode 2: QKV fused output. Q/K col-blocks (col0<2048) -> bf16 to Cout with
//         row stride QKN. V col-blocks -> in-LDS transpose (reusing staging
//         LDS, ld=136 for 16B alignment), then VtG[bh][d][t] coalesced.
// ---------------------------------------------------------------------------
__global__ __launch_bounds__(256) void gemm_kernel(const unsigned short* __restrict__ A,
    const unsigned short* __restrict__ Bt, const float* __restrict__ bias,
    void* __restrict__ Cout, unsigned short* __restrict__ VtG,
    int M, int N, int K, int mode)
{
    __shared__ unsigned short smem[17408];        // As(8192) + Bs(8192); V-epilogue reuses as [2][64][136]
    unsigned short* As = smem;
    unsigned short* Bs = smem + 8192;
    const int tid = threadIdx.x;
    const int lane = tid & 63;
    const int w = tid >> 6, wr = w >> 1, wc = w & 1;
    const int quad = lane >> 4, m16 = lane & 15;
    const int row0 = blockIdx.y * 128, col0 = blockIdx.x * 128;

    float bv[4];
#pragma unroll
    for (int ni = 0; ni < 4; ++ni)
        bv[ni] = bias[col0 + wc * 64 + ni * 16 + m16];

    floatx4 acc[4][4];
#pragma unroll
    for (int mi = 0; mi < 4; ++mi)
#pragma unroll
        for (int ni = 0; ni < 4; ++ni)
            acc[mi][ni] = (floatx4){0.f, 0.f, 0.f, 0.f};

    const int l3 = lane >> 3;                   // row-within-call (and row&7)
    const int swz = ((lane & 7) ^ l3) * 8;      // source chunk swizzle (elems)
    const unsigned short* gA[4];
    const unsigned short* gB[4];
    unsigned short* lA[4];
    unsigned short* lB[4];
#pragma unroll
    for (int i = 0; i < 4; ++i) {
        int c = w * 4 + i;                      // call id, rows c*8..c*8+7
        gA[i] = A  + (size_t)(row0 + c * 8 + l3) * K + swz;
        gB[i] = Bt + (size_t)(col0 + c * 8 + l3) * K + swz;
        lA[i] = &As[c * 512];
        lB[i] = &Bs[c * 512];
    }
    const int sw7 = m16 & 7;                    // frag-read swizzle key

    for (int k0 = 0; k0 < K; k0 += 64) {
#pragma unroll
        for (int i = 0; i < 4; ++i) {
            gload16(gA[i] + k0, lA[i]);
            gload16(gB[i] + k0, lB[i]);
        }
        __syncthreads();
#pragma unroll
        for (int s = 0; s < 2; ++s) {
            short8 af[4], bfr[4];
            const int ch = ((s * 4 + quad) ^ sw7) * 8;
#pragma unroll
            for (int mi = 0; mi < 4; ++mi)
                af[mi] = *(short8*)&As[(wr * 64 + mi * 16 + m16) * 64 + ch];
#pragma unroll
            for (int ni = 0; ni < 4; ++ni)
                bfr[ni] = *(short8*)&Bs[(wc * 64 + ni * 16 + m16) * 64 + ch];
#pragma unroll
            for (int mi = 0; mi < 4; ++mi)
#pragma unroll
                for (int ni = 0; ni < 4; ++ni)
                    acc[mi][ni] = __builtin_amdgcn_mfma_f32_16x16x32_bf16(af[mi], bfr[ni], acc[mi][ni], 0, 0, 0);
        }
        __syncthreads();
    }

    if (mode == 0) {
#pragma unroll
        for (int mi = 0; mi < 4; ++mi)
#pragma unroll
            for (int ni = 0; ni < 4; ++ni)
#pragma unroll
                for (int reg = 0; reg < 4; ++reg) {
                    int r = row0 + wr * 64 + mi * 16 + quad * 4 + reg;
                    int c = col0 + wc * 64 + ni * 16 + m16;
                    ((float*)Cout)[(size_t)r * N + c] = acc[mi][ni][reg] + bv[ni];
                }
    } else if (col0 < 2048) {
        // Q/K: bf16 rows at stride QKN
#pragma unroll
        for (int mi = 0; mi < 4; ++mi)
#pragma unroll
            for (int ni = 0; ni < 4; ++ni)
#pragma unroll
                for (int reg = 0; reg < 4; ++reg) {
                    int r = row0 + wr * 64 + mi * 16 + quad * 4 + reg;
                    int c = col0 + wc * 64 + ni * 16 + m16;
                    ((unsigned short*)Cout)[(size_t)r * QKN + c] = f2bf(acc[mi][ni][reg] + bv[ni]);
                }
    } else {
        // V: transpose in LDS -> VtG[bh][d][t]. vt[wc][d][lr], ld = 136.
        unsigned short* vt = smem;
        const int hb = (col0 - 2048) >> 6;      // head base (even)
#pragma unroll
        for (int mi = 0; mi < 4; ++mi)
#pragma unroll
            for (int ni = 0; ni < 4; ++ni) {
                const int d  = ni * 16 + m16;
                const int lr = wr * 64 + mi * 16 + quad * 4;
                unsigned* dst = (unsigned*)&vt[(wc * 64 + d) * 136 + lr];
                dst[0] = pkbf(acc[mi][ni][0] + bv[ni], acc[mi][ni][1] + bv[ni]);
                dst[1] = pkbf(acc[mi][ni][2] + bv[ni], acc[mi][ni][3] + bv[ni]);
            }
        __syncthreads();
        const int wsel = tid >> 7;              // head half
        const int d    = (tid >> 1) & 63;
        const int tseg = (tid & 1) * 64;
        const unsigned short* src = &vt[(wsel * 64 + d) * 136 + tseg];
        unsigned short* dstg = VtG
            + (size_t)((row0 >> 10) * Hz + hb + wsel) * (HDz * Tz)
            + (size_t)d * Tz + (row0 & 1023) + tseg;
#pragma unroll
        for (int k = 0; k < 8; ++k)
            *(short8*)&dstg[k * 8] = *(const short8*)&src[k * 8];
    }
}

// ---------------------------------------------------------------------------
// MFMA causal flash attention (unchanged from R8 except Q/K stride = QKN).
// Grid (8, 128), block 128 thr = 2 waves; block bx does q-tiles {15-bx, bx}.
// ---------------------------------------------------------------------------
__global__ __launch_bounds__(128) void attn_kernel(const unsigned short* __restrict__ qkb,
    const unsigned short* __restrict__ VtG, unsigned short* __restrict__ attb)
{
    __shared__ unsigned short Ks[2][64 * 64];   // [key][d swizzled]
    __shared__ unsigned short Vs[2][64 * 64];   // [d][key swizzled]

    const int bx = blockIdx.x;                  // 0..7
    const int bh = blockIdx.y;
    const int b = bh >> 4, h = bh & 15;
    const int tid = threadIdx.x, lane = tid & 63, w = tid >> 6;   // w in {0,1}
    const int quad = lane >> 4, m16 = lane & 15;
    const int qis[2] = {15 - bx, bx};           // big tile first

    const unsigned short* Kb = qkb + (size_t)(b * Tz) * QKN + Cz + h * HDz;
    const unsigned short* Vb = VtG + (size_t)bh * (HDz * Tz);

    const int l3 = lane >> 3, l7 = lane & 7;
    const int gsw = ((l7 ^ l3) << 3);           // staging source swizzle
    const int sw = m16 & 7;                     // read-side row swizzle key
    const int p0 = (quad ^ sw) << 3;            // K-frag group offset (elems)

    // ones A-frag for the l-sum MFMA: A[m=0][k]=1, else 0
    short8 onesf = (short8){0,0,0,0,0,0,0,0};
    if (m16 == 0) {
        const short one = (short)0x3F80;
        onesf = (short8){one,one,one,one,one,one,one,one};
    }

    int srow[4];
#pragma unroll
    for (int i = 0; i < 4; ++i) srow[i] = w * 32 + i * 8 + l3;

    // prologue: stage key-tile 0 into buf 0
#pragma unroll
    for (int i = 0; i < 4; ++i) {
        gload16(Kb + (size_t)srow[i] * QKN + gsw, &Ks[0][(w * 4 + i) * 512]);
        gload16(Vb + (size_t)srow[i] * Tz + gsw, &Vs[0][(w * 4 + i) * 512]);
    }

    int buf = 0;
    for (int t = 0; t < 2; ++t) {
        const int qi = qis[t];

        // Q B-frags: rows qi*64 + w*32 + mi*16 + m16
        short8 qf[2][2];
        int qrow[2];
#pragma unroll
        for (int mi = 0; mi < 2; ++mi) {
            qrow[mi] = qi * 64 + w * 32 + mi * 16 + m16;
            const size_t rq = (size_t)(b * Tz + qrow[mi]) * QKN + h * HDz;
            qf[mi][0] = *(const short8*)&qkb[rq + quad * 8];
            qf[mi][1] = *(const short8*)&qkb[rq + 32 + quad * 8];
        }

        floatx4 of[2][4];   // O^T accum: [d=dc*16+quad*4+reg][q=m16]
#pragma unroll
        for (int mi = 0; mi < 2; ++mi)
#pragma unroll
            for (int dc = 0; dc < 4; ++dc) of[mi][dc] = (floatx4){0.f, 0.f, 0.f, 0.f};
        floatx4 lsum[2];
        lsum[0] = (floatx4){0.f, 0.f, 0.f, 0.f};
        lsum[1] = (floatx4){0.f, 0.f, 0.f, 0.f};

        auto tile_body = [&](auto diag_c) {
            constexpr bool DIAG = decltype(diag_c)::value;
            short8 pf[2][2];
#pragma unroll
            for (int m0 = 0; m0 < 4; ++m0) {
                if (DIAG && w == 0 && m0 >= 2) continue;
                const unsigned short* kr = &Ks[buf][(m0 * 16 + m16) * 64];
                short8 kf0 = *(const short8*)&kr[p0];
                short8 kf1 = *(const short8*)&kr[p0 ^ 32];
#pragma unroll
                for (int mi = 0; mi < 2; ++mi) {
                    floatx4 st = (floatx4){0.f, 0.f, 0.f, 0.f};
                    st = __builtin_amdgcn_mfma_f32_16x16x32_bf16(kf0, qf[mi][0], st, 0, 0, 0);
                    st = __builtin_amdgcn_mfma_f32_16x16x32_bf16(kf1, qf[mi][1], st, 0, 0, 0);
                    float p[4];
#pragma unroll
                    for (int reg = 0; reg < 4; ++reg) {
                        p[reg] = exp2f(st[reg] * 0.18033688f);
                        if (DIAG) {
                            int key = m0 * 16 + quad * 4 + reg;
                            int qr  = w * 32 + mi * 16 + m16;
                            p[reg] = (key <= qr) ? p[reg] : 0.f;
                        }
                    }
                    unsigned* pp = (unsigned*)&pf[mi][m0 >> 1];
                    pp[(m0 & 1) * 2 + 0] = pkbf(p[0], p[1]);
                    pp[(m0 & 1) * 2 + 1] = pkbf(p[2], p[3]);
                }
            }
#pragma unroll
            for (int kg = 0; kg < 2; ++kg) {
                if (DIAG && w == 0 && kg == 1) continue;
#pragma unroll
                for (int mi = 0; mi < 2; ++mi)
                    lsum[mi] = __builtin_amdgcn_mfma_f32_16x16x32_bf16(onesf, pf[mi][kg], lsum[mi], 0, 0, 0);
#pragma unroll
                for (int dc = 0; dc < 4; ++dc) {
                    const unsigned short* vrow = &Vs[buf][(dc * 16 + m16) * 64];
                    const int g0 = kg * 4 + (quad >> 1);
                    const int off = (quad & 1) * 4;
                    short4v v0 = *(const short4v*)&vrow[((g0 ^ sw) << 3) + off];
                    short4v v1 = *(const short4v*)&vrow[(((g0 + 2) ^ sw) << 3) + off];
                    short8 vf;
                    vf[0] = v0[0]; vf[1] = v0[1]; vf[2] = v0[2]; vf[3] = v0[3];
                    vf[4] = v1[0]; vf[5] = v1[1]; vf[6] = v1[2]; vf[7] = v1[3];
#pragma unroll
                    for (int mi = 0; mi < 2; ++mi)
                        of[mi][dc] = __builtin_amdgcn_mfma_f32_16x16x32_bf16(vf, pf[mi][kg], of[mi][dc], 0, 0, 0);
                }
            }
        };

        for (int ki = 0; ki <= qi; ++ki) {
            __syncthreads();
            const int nk = (ki < qi) ? (ki + 1) : (t == 0 ? 0 : -1);
            if (nk >= 0) {
                const size_t ko = (size_t)nk * 64;
#pragma unroll
                for (int i = 0; i < 4; ++i) {
                    gload16(Kb + (ko + srow[i]) * QKN + gsw, &Ks[buf ^ 1][(w * 4 + i) * 512]);
                    gload16(Vb + (size_t)srow[i] * Tz + ko + gsw, &Vs[buf ^ 1][(w * 4 + i) * 512]);
                }
            }
            if (ki == qi) tile_body(std::true_type{});
            else          tile_body(std::false_type{});
            buf ^= 1;
        }

#pragma unroll
        for (int mi = 0; mi < 2; ++mi) {
            const float l = __shfl(lsum[mi][0], m16);   // from lanes 0..15
            const float inv = 1.f / l;
            const size_t orow = (size_t)(b * Tz + qrow[mi]) * Cz + h * HDz;
#pragma unroll
            for (int dc = 0; dc < 4; ++dc) {
                ushort4 o;
                o.x = f2bf(of[mi][dc][0] * inv);
                o.y = f2bf(of[mi][dc][1] * inv);
                o.z = f2bf(of[mi][dc][2] * inv);
                o.w = f2bf(of[mi][dc][3] * inv);
                *(ushort4*)&attb[orow + dc * 16 + quad * 4] = o;
            }
        }
    }
}

// ---------------------------------------------------------------------------
extern "C" void kernel_launch(void* const* d_in, const int* in_sizes, int n_in,
                              void* d_out, int out_size, void* d_ws, size_t ws_size,
                              hipStream_t stream)
{
    const float* x     = (const float*)d_in[0];
    const float* Wqkv  = (const float*)d_in[1];
    const float* bqkv  = (const float*)d_in[2];
    const float* Wproj = (const float*)d_in[3];
    const float* bproj = (const float*)d_in[4];
    float* out = (float*)d_out;

    // Workspace (76 MB): attb aliases xb (xb fully consumed by gemm1 before
    // attn writes attb; stream-ordered, re-poison-safe).
    unsigned short* xb     = (unsigned short*)d_ws;              // 16 MB
    unsigned short* Wqkvt  = xb + (size_t)Mz * Cz;               //  6 MB
    unsigned short* Wprojt = Wqkvt + (size_t)N1 * Cz;            //  2 MB
    unsigned short* qkb    = Wprojt + (size_t)Cz * Cz;           // 32 MB
    unsigned short* VtG    = qkb + (size_t)Mz * QKN;             // 16 MB
    unsigned short* attb   = xb;                                 // alias

    prep_kernel<<<12288, 256, 0, stream>>>(x, xb, Wqkv, Wqkvt, Wproj, Wprojt);

    // QKV GEMM with fused Q/K store + V transpose-store
    gemm_kernel<<<dim3(N1 / 128, Mz / 128), 256, 0, stream>>>(
        xb, Wqkvt, bqkv, qkb, VtG, Mz, N1, Cz, 2);

    attn_kernel<<<dim3(8, Bz * Hz), 128, 0, stream>>>(qkb, VtG, attb);

    gemm_kernel<<<dim3(Cz / 128, Mz / 128), 256, 0, stream>>>(
        attb, Wprojt, bproj, out, nullptr, Mz, Cz, Cz, 0);
}

// Round 10
// 245.263 us; speedup vs baseline: 1.0232x; 1.0093x over previous
//
#include <hip/hip_runtime.h>
#include <hip/hip_bf16.h>
#include <math.h>
#include <type_traits>

#define Bz 8
#define Tz 1024
#define Cz 1024
#define Hz 16
#define HDz 64
#define Mz (Bz*Tz)        // 8192 tokens
#define N1 (3*Cz)         // 3072 qkv width
#define QKN 2048          // Q+K buffer row stride

typedef __attribute__((ext_vector_type(8))) short short8;
typedef __attribute__((ext_vector_type(4))) short short4v;
typedef __attribute__((ext_vector_type(4))) float floatx4;

__device__ __forceinline__ unsigned short f2bf(float f) {
    unsigned u = __float_as_uint(f);
    return (unsigned short)((u + 0x7FFFu + ((u >> 16) & 1u)) >> 16);
}

// pack two f32 -> bf16x2 dword (RNE; v_cvt_pk_bf16_f32 on gfx950)
__device__ __forceinline__ unsigned pkbf(float a, float b) {
    __hip_bfloat162 h = __float22bfloat162_rn(make_float2(a, b));
    return *(unsigned*)&h;
}

// async global->LDS, 16 B per lane, dest = uniform base + lane*16
__device__ __forceinline__ void gload16(const void* g, void* l) {
    __builtin_amdgcn_global_load_lds(
        (const __attribute__((address_space(1))) unsigned int*)g,
        (__attribute__((address_space(3))) unsigned int*)l, 16, 0, 0);
}

// ---------------------------------------------------------------------------
// Merged prep: x fp32->bf16  +  Wqkv / Wproj transpose+convert.
// blockIdx.x ranges:  [0,8192) cvt   [8192,11264) Wqkv   [11264,12288) Wproj
// ---------------------------------------------------------------------------
__global__ __launch_bounds__(256) void prep_kernel(
    const float* __restrict__ x, unsigned short* __restrict__ xb,
    const float* __restrict__ Wqkv, unsigned short* __restrict__ Wqkvt,
    const float* __restrict__ Wproj, unsigned short* __restrict__ Wprojt)
{
    __shared__ float tile[32][33];
    const int bid = blockIdx.x;
    const int tid = threadIdx.x;
    if (bid < 8192) {
        int i = bid * 256 + tid;                  // 4 elems each
        float4 v = *(const float4*)&x[(size_t)i * 4];
        ushort4 o;
        o.x = f2bf(v.x); o.y = f2bf(v.y); o.z = f2bf(v.z); o.w = f2bf(v.w);
        *(ushort4*)&xb[(size_t)i * 4] = o;
        return;
    }
    const float* W; unsigned short* Wt; int K, N, n0, k0;
    if (bid < 11264) {
        int b = bid - 8192;  W = Wqkv;  Wt = Wqkvt;  K = Cz; N = N1;
        n0 = (b % 96) * 32;  k0 = (b / 96) * 32;
    } else {
        int b = bid - 11264; W = Wproj; Wt = Wprojt; K = Cz; N = Cz;
        n0 = (b % 32) * 32;  k0 = (b / 32) * 32;
    }
    const int tx = tid & 31, ty = tid >> 5;       // (32,8)
#pragma unroll
    for (int i = 0; i < 4; ++i)
        tile[ty + i * 8][tx] = W[(size_t)(k0 + ty + i * 8) * N + n0 + tx];
    __syncthreads();
#pragma unroll
    for (int i = 0; i < 4; ++i)
        Wt[(size_t)(n0 + ty + i * 8) * K + k0 + tx] = f2bf(tile[tx][ty + i * 8]);
}

// ---------------------------------------------------------------------------
// bf16 MFMA GEMM: C = A[M][K] @ Bt[N][K]^T + bias. 128x128 tile, BK=64,
// XOR-chunk source swizzle on staging, unswizzled at fragment read.
// mode 0: fp32 out, row stride N (proj).
// mode 2: QKV fused output. Q/K col-blocks (col0<2048) -> bf16 to Cout with
//         row stride QKN. V col-blocks -> direct register-path transposed
//         stores to VtG[bh][d][t] (C-layout rows are t-contiguous: 8-B
//         dwordx2 per mi/ni; no LDS, no barriers).
// ---------------------------------------------------------------------------
__global__ __launch_bounds__(256) void gemm_kernel(const unsigned short* __restrict__ A,
    const unsigned short* __restrict__ Bt, const float* __restrict__ bias,
    void* __restrict__ Cout, unsigned short* __restrict__ VtG,
    int M, int N, int K, int mode)
{
    __shared__ unsigned short As[128 * 64];
    __shared__ unsigned short Bs[128 * 64];
    const int tid = threadIdx.x;
    const int lane = tid & 63;
    const int w = tid >> 6, wr = w >> 1, wc = w & 1;
    const int quad = lane >> 4, m16 = lane & 15;
    const int row0 = blockIdx.y * 128, col0 = blockIdx.x * 128;

    float bv[4];
#pragma unroll
    for (int ni = 0; ni < 4; ++ni)
        bv[ni] = bias[col0 + wc * 64 + ni * 16 + m16];

    floatx4 acc[4][4];
#pragma unroll
    for (int mi = 0; mi < 4; ++mi)
#pragma unroll
        for (int ni = 0; ni < 4; ++ni)
            acc[mi][ni] = (floatx4){0.f, 0.f, 0.f, 0.f};

    const int l3 = lane >> 3;                   // row-within-call (and row&7)
    const int swz = ((lane & 7) ^ l3) * 8;      // source chunk swizzle (elems)
    const unsigned short* gA[4];
    const unsigned short* gB[4];
    unsigned short* lA[4];
    unsigned short* lB[4];
#pragma unroll
    for (int i = 0; i < 4; ++i) {
        int c = w * 4 + i;                      // call id, rows c*8..c*8+7
        gA[i] = A  + (size_t)(row0 + c * 8 + l3) * K + swz;
        gB[i] = Bt + (size_t)(col0 + c * 8 + l3) * K + swz;
        lA[i] = &As[c * 512];
        lB[i] = &Bs[c * 512];
    }
    const int sw7 = m16 & 7;                    // frag-read swizzle key

    for (int k0 = 0; k0 < K; k0 += 64) {
#pragma unroll
        for (int i = 0; i < 4; ++i) {
            gload16(gA[i] + k0, lA[i]);
            gload16(gB[i] + k0, lB[i]);
        }
        __syncthreads();
#pragma unroll
        for (int s = 0; s < 2; ++s) {
            short8 af[4], bfr[4];
            const int ch = ((s * 4 + quad) ^ sw7) * 8;
#pragma unroll
            for (int mi = 0; mi < 4; ++mi)
                af[mi] = *(short8*)&As[(wr * 64 + mi * 16 + m16) * 64 + ch];
#pragma unroll
            for (int ni = 0; ni < 4; ++ni)
                bfr[ni] = *(short8*)&Bs[(wc * 64 + ni * 16 + m16) * 64 + ch];
#pragma unroll
            for (int mi = 0; mi < 4; ++mi)
#pragma unroll
                for (int ni = 0; ni < 4; ++ni)
                    acc[mi][ni] = __builtin_amdgcn_mfma_f32_16x16x32_bf16(af[mi], bfr[ni], acc[mi][ni], 0, 0, 0);
        }
        __syncthreads();
    }

    if (mode == 0) {
#pragma unroll
        for (int mi = 0; mi < 4; ++mi)
#pragma unroll
            for (int ni = 0; ni < 4; ++ni)
#pragma unroll
                for (int reg = 0; reg < 4; ++reg) {
                    int r = row0 + wr * 64 + mi * 16 + quad * 4 + reg;
                    int c = col0 + wc * 64 + ni * 16 + m16;
                    ((float*)Cout)[(size_t)r * N + c] = acc[mi][ni][reg] + bv[ni];
                }
    } else if (col0 < 2048) {
        // Q/K: bf16 rows at stride QKN
#pragma unroll
        for (int mi = 0; mi < 4; ++mi)
#pragma unroll
            for (int ni = 0; ni < 4; ++ni)
#pragma unroll
                for (int reg = 0; reg < 4; ++reg) {
                    int r = row0 + wr * 64 + mi * 16 + quad * 4 + reg;
                    int c = col0 + wc * 64 + ni * 16 + m16;
                    ((unsigned short*)Cout)[(size_t)r * QKN + c] = f2bf(acc[mi][ni][reg] + bv[ni]);
                }
    } else {
        // V: direct transposed store. Lane holds 4 consecutive tokens for
        // feature d = (head half wc)*64-block col. VtG[bh][d][t], 8 B runs.
        const int hb = (col0 - 2048) >> 6;      // head base (even), + wc
        const int bq = row0 >> 10;              // batch
        const int hsel = hb + wc;
        const int d = (hsel & 15) * 0;          // silence unused warn path
        (void)d;
#pragma unroll
        for (int ni = 0; ni < 4; ++ni) {
            const int dd = ni * 16 + m16;       // feature within head
            unsigned short* drow = VtG
                + (size_t)(bq * Hz + hsel) * (HDz * Tz)
                + (size_t)dd * Tz + (row0 & 1023);
#pragma unroll
            for (int mi = 0; mi < 4; ++mi) {
                const int t = wr * 64 + mi * 16 + quad * 4;
                unsigned pk[2];
                pk[0] = pkbf(acc[mi][ni][0] + bv[ni], acc[mi][ni][1] + bv[ni]);
                pk[1] = pkbf(acc[mi][ni][2] + bv[ni], acc[mi][ni][3] + bv[ni]);
                *(uint2*)&drow[t] = *(uint2*)pk;
            }
        }
    }
}

// ---------------------------------------------------------------------------
// MFMA causal flash attention (unchanged from R9).
// Grid (8, 128), block 128 thr = 2 waves; block bx does q-tiles {15-bx, bx}.
// ---------------------------------------------------------------------------
__global__ __launch_bounds__(128) void attn_kernel(const unsigned short* __restrict__ qkb,
    const unsigned short* __restrict__ VtG, unsigned short* __restrict__ attb)
{
    __shared__ unsigned short Ks[2][64 * 64];   // [key][d swizzled]
    __shared__ unsigned short Vs[2][64 * 64];   // [d][key swizzled]

    const int bx = blockIdx.x;                  // 0..7
    const int bh = blockIdx.y;
    const int b = bh >> 4, h = bh & 15;
    const int tid = threadIdx.x, lane = tid & 63, w = tid >> 6;   // w in {0,1}
    const int quad = lane >> 4, m16 = lane & 15;
    const int qis[2] = {15 - bx, bx};           // big tile first

    const unsigned short* Kb = qkb + (size_t)(b * Tz) * QKN + Cz + h * HDz;
    const unsigned short* Vb = VtG + (size_t)bh * (HDz * Tz);

    const int l3 = lane >> 3, l7 = lane & 7;
    const int gsw = ((l7 ^ l3) << 3);           // staging source swizzle
    const int sw = m16 & 7;                     // read-side row swizzle key
    const int p0 = (quad ^ sw) << 3;            // K-frag group offset (elems)

    // ones A-frag for the l-sum MFMA: A[m=0][k]=1, else 0
    short8 onesf = (short8){0,0,0,0,0,0,0,0};
    if (m16 == 0) {
        const short one = (short)0x3F80;
        onesf = (short8){one,one,one,one,one,one,one,one};
    }

    int srow[4];
#pragma unroll
    for (int i = 0; i < 4; ++i) srow[i] = w * 32 + i * 8 + l3;

    // prologue: stage key-tile 0 into buf 0
#pragma unroll
    for (int i = 0; i < 4; ++i) {
        gload16(Kb + (size_t)srow[i] * QKN + gsw, &Ks[0][(w * 4 + i) * 512]);
        gload16(Vb + (size_t)srow[i] * Tz + gsw, &Vs[0][(w * 4 + i) * 512]);
    }

    int buf = 0;
    for (int t = 0; t < 2; ++t) {
        const int qi = qis[t];

        // Q B-frags: rows qi*64 + w*32 + mi*16 + m16
        short8 qf[2][2];
        int qrow[2];
#pragma unroll
        for (int mi = 0; mi < 2; ++mi) {
            qrow[mi] = qi * 64 + w * 32 + mi * 16 + m16;
            const size_t rq = (size_t)(b * Tz + qrow[mi]) * QKN + h * HDz;
            qf[mi][0] = *(const short8*)&qkb[rq + quad * 8];
            qf[mi][1] = *(const short8*)&qkb[rq + 32 + quad * 8];
        }

        floatx4 of[2][4];   // O^T accum: [d=dc*16+quad*4+reg][q=m16]
#pragma unroll
        for (int mi = 0; mi < 2; ++mi)
#pragma unroll
            for (int dc = 0; dc < 4; ++dc) of[mi][dc] = (floatx4){0.f, 0.f, 0.f, 0.f};
        floatx4 lsum[2];
        lsum[0] = (floatx4){0.f, 0.f, 0.f, 0.f};
        lsum[1] = (floatx4){0.f, 0.f, 0.f, 0.f};

        auto tile_body = [&](auto diag_c) {
            constexpr bool DIAG = decltype(diag_c)::value;
            short8 pf[2][2];
#pragma unroll
            for (int m0 = 0; m0 < 4; ++m0) {
                if (DIAG && w == 0 && m0 >= 2) continue;
                const unsigned short* kr = &Ks[buf][(m0 * 16 + m16) * 64];
                short8 kf0 = *(const short8*)&kr[p0];
                short8 kf1 = *(const short8*)&kr[p0 ^ 32];
#pragma unroll
                for (int mi = 0; mi < 2; ++mi) {
                    floatx4 st = (floatx4){0.f, 0.f, 0.f, 0.f};
                    st = __builtin_amdgcn_mfma_f32_16x16x32_bf16(kf0, qf[mi][0], st, 0, 0, 0);
                    st = __builtin_amdgcn_mfma_f32_16x16x32_bf16(kf1, qf[mi][1], st, 0, 0, 0);
                    float p[4];
#pragma unroll
                    for (int reg = 0; reg < 4; ++reg) {
                        p[reg] = exp2f(st[reg] * 0.18033688f);
                        if (DIAG) {
                            int key = m0 * 16 + quad * 4 + reg;
                            int qr  = w * 32 + mi * 16 + m16;
                            p[reg] = (key <= qr) ? p[reg] : 0.f;
                        }
                    }
                    unsigned* pp = (unsigned*)&pf[mi][m0 >> 1];
                    pp[(m0 & 1) * 2 + 0] = pkbf(p[0], p[1]);
                    pp[(m0 & 1) * 2 + 1] = pkbf(p[2], p[3]);
                }
            }
#pragma unroll
            for (int kg = 0; kg < 2; ++kg) {
                if (DIAG && w == 0 && kg == 1) continue;
#pragma unroll
                for (int mi = 0; mi < 2; ++mi)
                    lsum[mi] = __builtin_amdgcn_mfma_f32_16x16x32_bf16(onesf, pf[mi][kg], lsum[mi], 0, 0, 0);
#pragma unroll
                for (int dc = 0; dc < 4; ++dc) {
                    const unsigned short* vrow = &Vs[buf][(dc * 16 + m16) * 64];
                    const int g0 = kg * 4 + (quad >> 1);
                    const int off = (quad & 1) * 4;
                    short4v v0 = *(const short4v*)&vrow[((g0 ^ sw) << 3) + off];
                    short4v v1 = *(const short4v*)&vrow[(((g0 + 2) ^ sw) << 3) + off];
                    short8 vf;
                    vf[0] = v0[0]; vf[1] = v0[1]; vf[2] = v0[2]; vf[3] = v0[3];
                    vf[4] = v1[0]; vf[5] = v1[1]; vf[6] = v1[2]; vf[7] = v1[3];
#pragma unroll
                    for (int mi = 0; mi < 2; ++mi)
                        of[mi][dc] = __builtin_amdgcn_mfma_f32_16x16x32_bf16(vf, pf[mi][kg], of[mi][dc], 0, 0, 0);
                }
            }
        };

        for (int ki = 0; ki <= qi; ++ki) {
            __syncthreads();
            const int nk = (ki < qi) ? (ki + 1) : (t == 0 ? 0 : -1);
            if (nk >= 0) {
                const size_t ko = (size_t)nk * 64;
#pragma unroll
                for (int i = 0; i < 4; ++i) {
                    gload16(Kb + (ko + srow[i]) * QKN + gsw, &Ks[buf ^ 1][(w * 4 + i) * 512]);
                    gload16(Vb + (size_t)srow[i] * Tz + ko + gsw, &Vs[buf ^ 1][(w * 4 + i) * 512]);
                }
            }
            if (ki == qi) tile_body(std::true_type{});
            else          tile_body(std::false_type{});
            buf ^= 1;
        }

#pragma unroll
        for (int mi = 0; mi < 2; ++mi) {
            const float l = __shfl(lsum[mi][0], m16);   // from lanes 0..15
            const float inv = 1.f / l;
            const size_t orow = (size_t)(b * Tz + qrow[mi]) * Cz + h * HDz;
#pragma unroll
            for (int dc = 0; dc < 4; ++dc) {
                ushort4 o;
                o.x = f2bf(of[mi][dc][0] * inv);
                o.y = f2bf(of[mi][dc][1] * inv);
                o.z = f2bf(of[mi][dc][2] * inv);
                o.w = f2bf(of[mi][dc][3] * inv);
                *(ushort4*)&attb[orow + dc * 16 + quad * 4] = o;
            }
        }
    }
}

// ---------------------------------------------------------------------------
extern "C" void kernel_launch(void* const* d_in, const int* in_sizes, int n_in,
                              void* d_out, int out_size, void* d_ws, size_t ws_size,
                              hipStream_t stream)
{
    const float* x     = (const float*)d_in[0];
    const float* Wqkv  = (const float*)d_in[1];
    const float* bqkv  = (const float*)d_in[2];
    const float* Wproj = (const float*)d_in[3];
    const float* bproj = (const float*)d_in[4];
    float* out = (float*)d_out;

    // Workspace (76 MB): attb aliases xb (xb fully consumed by gemm1 before
    // attn writes attb; stream-ordered, re-poison-safe).
    unsigned short* xb     = (unsigned short*)d_ws;              // 16 MB
    unsigned short* Wqkvt  = xb + (size_t)Mz * Cz;               //  6 MB
    unsigned short* Wprojt = Wqkvt + (size_t)N1 * Cz;            //  2 MB
    unsigned short* qkb    = Wprojt + (size_t)Cz * Cz;           // 32 MB
    unsigned short* VtG    = qkb + (size_t)Mz * QKN;             // 16 MB
    unsigned short* attb   = xb;                                 // alias

    prep_kernel<<<12288, 256, 0, stream>>>(x, xb, Wqkv, Wqkvt, Wproj, Wprojt);

    // QKV GEMM with fused Q/K store + register-path V transpose-store
    gemm_kernel<<<dim3(N1 / 128, Mz / 128), 256, 0, stream>>>(
        xb, Wqkvt, bqkv, qkb, VtG, Mz, N1, Cz, 2);

    attn_kernel<<<dim3(8, Bz * Hz), 128, 0, stream>>>(qkb, VtG, attb);

    gemm_kernel<<<dim3(Cz / 128, Mz / 128), 256, 0, stream>>>(
        attb, Wprojt, bproj, out, nullptr, Mz, Cz, Cz, 0);
}